// Round 1
// 1037.731 us; speedup vs baseline: 1.0329x; 1.0329x over previous
//
#include <hip/hip_runtime.h>
#include <hip/hip_bf16.h>

// Problem constants
#define BB 16
#define LL 1024
#define DD 384
#define FF 1536
#define KK 3
#define T_OUT 10240
#define MAX_DUR 10

#define PADL 1026                 // per-batch padded rows: [0]=zero, [1..1024]=data, [1025]=zero
#define LO_SCALE 2048.0f          // 2^11: keeps lo parts out of fp16-denormal range
#define LO_INV   4.8828125e-4f    // 2^-11

typedef _Float16 f16x8 __attribute__((ext_vector_type(8)));
typedef float    f32x4 __attribute__((ext_vector_type(4)));

__device__ __forceinline__ void gll16(const void* g, void* l) {
    __builtin_amdgcn_global_load_lds(
        (const __attribute__((address_space(1))) void*)g,
        (__attribute__((address_space(3))) void*)l, 16, 0, 0);
}

__device__ __forceinline__ void split_write(float v, _Float16* hi, _Float16* lo, size_t off) {
    _Float16 h = (_Float16)v;
    hi[off] = h;
    lo[off] = (_Float16)((v - (float)h) * LO_SCALE);
}

__device__ __forceinline__ float split_read(const _Float16* hi, const _Float16* lo, size_t off) {
    return (float)hi[off] + (float)lo[off] * LO_INV;
}

// ---- weight pack: (O,I,3) -> MFMA-fragment-major hi/lo --------------------
// frag layout: [o_tile][ktl][lane][e8], 8 halfs per lane (16 B), so a wave's
// b-frag load is base + lane*16 (one coalesced global_load_dwordx4).
// ktl ordering matches the GEMM k-loop: kseg = ktl%3 (fastest), d0 = (ktl/3)*32.
// lane: n_local = lane&15, k-quad = lane>>4; elem e: koff = kq*8 + e.
__global__ void wfrag_k(const float* __restrict__ w, _Float16* __restrict__ hi,
                        _Float16* __restrict__ lo, int O, int I) {
    int id = blockIdx.x * 256 + threadIdx.x;
    int total = O * 3 * I;
    if (id >= total) return;
    int e = id & 7;
    int lane = (id >> 3) & 63;
    int rest = id >> 9;              // o_tile * nKT + ktl
    int nKT = (3 * I) >> 5;
    int ktl = rest % nKT;
    int ot = rest / nKT;
    int o = ot * 16 + (lane & 15);
    int koff = ((lane >> 4) << 3) + e;
    int kseg = ktl % 3;
    int i = (ktl / 3) * 32 + koff;
    float v = w[(o * I + i) * 3 + kseg];
    split_write(v, hi, lo, id);
}

// ---------------- y split into padded hi/lo layout ---------------------------
__global__ void ysplit_k(const float* __restrict__ y, _Float16* __restrict__ hi,
                         _Float16* __restrict__ lo) {
    int id = blockIdx.x * 256 + threadIdx.x;     // BB*PADL*DD
    if (id >= BB * PADL * DD) return;
    int d = id % DD;
    int r = id / DD;
    int b = r / PADL;
    int lr = r - b * PADL;
    float v = 0.f;
    if (lr >= 1 && lr <= LL) v = y[((size_t)(b << 10) + (lr - 1)) * DD + d];
    split_write(v, hi, lo, id);
}

// ---------------- zero the halo pad rows of a padded split buffer ------------
__global__ void padzero_k(_Float16* __restrict__ hi, _Float16* __restrict__ lo, int width) {
    int id = blockIdx.x * 256 + threadIdx.x;     // BB*2*width
    if (id >= BB * 2 * width) return;
    int b = id / (2 * width);
    int rem = id - b * 2 * width;
    int row = (rem / width) ? (PADL - 1) : 0;
    int c = rem % width;
    size_t off = (size_t)(b * PADL + row) * width + c;
    hi[off] = (_Float16)0.f;
    lo[off] = (_Float16)0.f;
}

// ---------------- split-fp16 MFMA conv-GEMM ----------------------------------
// Template MI = fragment rows per wave / 16 (MI=4 -> BM=128, MI=2 -> BM=64).
// Pipeline (T3/T4-style counted vmcnt, no vmcnt(0) in the main loop):
//   4 LDS buffers, A staged 2 k-tiles ahead via global_load_lds,
//   B register double-buffered 1 k-tile ahead.
//   Per half: issue B(kt+1) [8 vmem] then A(kt+2) [4*NIT/2.. = 2*NIT vmem],
//   s_waitcnt vmcnt(8+4*NIT)  // drains A(kt),B(kt); keeps B(kt+1),A(kt+1),A(kt+2)
//   raw s_barrier (ONE per k-tile; loads stay in flight across it),
//   compute(kt) with s_setprio(1) around the MFMA cluster.
template<int MI>
__global__ __launch_bounds__(256, 2) void gemm_split(
        const _Float16* __restrict__ Ahi, const _Float16* __restrict__ Alo,
        const _Float16* __restrict__ WfH, const _Float16* __restrict__ WfL,
        const float* __restrict__ bias,
        _Float16* __restrict__ Ohi, _Float16* __restrict__ Olo,
        int Cin, int Cout, int Ktot, int nN) {
    constexpr int BM   = MI * 32;          // block M-rows (128 or 64)
    constexpr int BUFH = MI * 1024;        // halfs per comp per buffer (4096 / 2048)
    constexpr int NIT  = MI / 2;           // stage iters per comp per wave (2 / 1)
    constexpr int VMK  = 8 + 4 * NIT;      // counted-vmcnt keep (16 / 12)
    __shared__ _Float16 lds_h[8 * BUFH];   // 4 buffers x (Ahi BUFH | Alo BUFH)
    const int tid = threadIdx.x;
    const int lane = tid & 63;
    const int w = tid >> 6;
    const int lm = lane & 15, lq = lane >> 4;
    // XCD-aware remap: group-of-4 m-tiles, n fastest inside the group
    const int xcd = blockIdx.x & 7;
    const int t2 = blockIdx.x >> 3;
    const int g  = t2 / (4 * nN);
    const int r  = t2 - g * (4 * nN);
    const int n_t = r >> 2;
    const int mi  = r & 3;
    const int m_t = ((g * 4 + mi) << 3) + xcd;
    const int m0 = m_t * BM;
    const int n0 = n_t << 7;
    const int b = m0 >> 10;
    const int l0 = m0 & 1023;
    const int rowBase = b * PADL + l0;           // + m + kseg = padded source row
    const int wm = (w >> 1) * (MI * 16), wn = (w & 1) * 64;

    f32x4 accM[MI][4], accC[MI][4];
    const f32x4 zz = {0.f, 0.f, 0.f, 0.f};
    #pragma unroll
    for (int i = 0; i < MI; ++i)
        #pragma unroll
        for (int jj = 0; jj < 4; ++jj) { accM[i][jj] = zz; accC[i][jj] = zz; }

    const int nKT = Ktot >> 5;

    // stage A k-tile kt into LDS buffer bidx (BM*4 16B-chunks per comp)
    auto stageA = [&](int kt, int bidx) {
        int kseg = kt % 3;
        int d0 = (kt / 3) << 5;
        #pragma unroll
        for (int it = 0; it < NIT; ++it) {
            int s = (w * NIT + it) * 64 + lane;  // 16B-chunk index 0..BM*4-1
            int p = s >> 3, sl = s & 7;
            int t = sl ^ (p & 7);
            int m = p * 2 + (t >> 2);
            int k8 = t & 3;
            size_t aoff = (size_t)(rowBase + m + kseg) * Cin + d0 + k8 * 8;
            _Float16* lbase = lds_h + (size_t)bidx * (2 * BUFH) + (size_t)(w * NIT + it) * 512;
            gll16(Ahi + aoff, lbase);
            gll16(Alo + aoff, lbase + BUFH);
        }
    };

    // B fragment load for k-tile kt (clamped; always in-bounds)
    auto loadB = [&](int kt, f16x8* bH, f16x8* bL) {
        int ktc = kt < nKT ? kt : nKT - 1;
        #pragma unroll
        for (int jj = 0; jj < 4; ++jj) {
            int ntg = (n0 + wn + jj * 16) >> 4;
            size_t boff = (((size_t)ntg * nKT + ktc) * 64 + lane) * 8;
            bH[jj] = *(const f16x8*)(WfH + boff);
            bL[jj] = *(const f16x8*)(WfL + boff);
        }
    };

    // MFMA phase for one staged k-tile (i-outer: one A frag pair live at a time)
    auto compute = [&](const _Float16* lb, const f16x8* bH, const f16x8* bL) {
        __builtin_amdgcn_s_setprio(1);
        #pragma unroll
        for (int i = 0; i < MI; ++i) {
            int m = wm + i * 16 + lm;
            int p = m >> 1;
            int sl = (((m & 1) << 2) | lq) ^ (p & 7);
            int off = p * 64 + sl * 8;
            f16x8 aH = *(const f16x8*)(lb + off);
            f16x8 aL = *(const f16x8*)(lb + BUFH + off);
            #pragma unroll
            for (int jj = 0; jj < 4; ++jj) {
                accM[i][jj] = __builtin_amdgcn_mfma_f32_16x16x32_f16(aH, bH[jj], accM[i][jj], 0, 0, 0);
                accC[i][jj] = __builtin_amdgcn_mfma_f32_16x16x32_f16(aH, bL[jj], accC[i][jj], 0, 0, 0);
                accC[i][jj] = __builtin_amdgcn_mfma_f32_16x16x32_f16(aL, bH[jj], accC[i][jj], 0, 0, 0);
            }
        }
        __builtin_amdgcn_s_setprio(0);
    };

    f16x8 b0H[4], b0L[4], b1H[4], b1L[4];
    // prologue: A(0)->buf0, B(0)->b0, A(1)->buf1   (matches steady issue stream)
    stageA(0, 0);
    loadB(0, b0H, b0L);
    stageA(1, 1);
    for (int kt = 0; kt < nKT; kt += 2) {
        // ---- half: process kt (even) -------------------------------------
        loadB(kt + 1, b1H, b1L);                               // B(kt+1) [8]
        stageA(kt + 2 < nKT ? kt + 2 : nKT - 1, (kt + 2) & 3); // A(kt+2) [2*NIT]
        __builtin_amdgcn_sched_barrier(0);
        asm volatile("s_waitcnt vmcnt(%0)" :: "i"(VMK) : "memory");
        __builtin_amdgcn_s_barrier();
        __builtin_amdgcn_sched_barrier(0);
        compute(lds_h + (size_t)(kt & 3) * (2 * BUFH), b0H, b0L);
        // ---- half: process kt+1 (odd) ------------------------------------
        loadB(kt + 2, b0H, b0L);                               // B(kt+2) [8]
        stageA(kt + 3 < nKT ? kt + 3 : nKT - 1, (kt + 3) & 3); // A(kt+3) [2*NIT]
        __builtin_amdgcn_sched_barrier(0);
        asm volatile("s_waitcnt vmcnt(%0)" :: "i"(VMK) : "memory");
        __builtin_amdgcn_s_barrier();
        __builtin_amdgcn_sched_barrier(0);
        compute(lds_h + (size_t)((kt + 1) & 3) * (2 * BUFH), b1H, b1L);
    }
    // epilogue: bias + relu + re-split to padded hi/lo output
    #pragma unroll
    for (int i = 0; i < MI; ++i)
        #pragma unroll
        for (int jj = 0; jj < 4; ++jj) {
            int n_g = n0 + wn + jj * 16 + lm;
            float bv = bias[n_g];
            #pragma unroll
            for (int rr = 0; rr < 4; ++rr) {
                int l = l0 + wm + i * 16 + lq * 4 + rr;
                float v = accM[i][jj][rr] + accC[i][jj][rr] * LO_INV + bv;
                v = fmaxf(v, 0.f);
                size_t off = (size_t)(b * PADL + 1 + l) * Cout + n_g;
                split_write(v, Ohi, Olo, off);
            }
        }
}

// ---------------- layernorm in place on split buffer (width 384) -------------
__global__ __launch_bounds__(128) void ln_split_k(
        _Float16* __restrict__ hi, _Float16* __restrict__ lo,
        const float* __restrict__ g, const float* __restrict__ be) {
    const int row = blockIdx.x;
    const int b = row >> 10, l = row & 1023;
    const size_t base = (size_t)(b * PADL + 1 + l) * DD;
    const int tid = threadIdx.x;
    float v0 = split_read(hi, lo, base + tid);
    float v1 = split_read(hi, lo, base + tid + 128);
    float v2 = split_read(hi, lo, base + tid + 256);

    __shared__ float sh[2];
    float s = v0 + v1 + v2;
    #pragma unroll
    for (int o = 32; o > 0; o >>= 1) s += __shfl_down(s, o, 64);
    if ((tid & 63) == 0) sh[tid >> 6] = s;
    __syncthreads();
    float mu = (sh[0] + sh[1]) * (1.f / DD);
    __syncthreads();
    float d0 = v0 - mu, d1 = v1 - mu, d2 = v2 - mu;
    float q = d0 * d0 + d1 * d1 + d2 * d2;
    #pragma unroll
    for (int o = 32; o > 0; o >>= 1) q += __shfl_down(q, o, 64);
    if ((tid & 63) == 0) sh[tid >> 6] = q;
    __syncthreads();
    float var = (sh[0] + sh[1]) * (1.f / DD);
    float rs = rsqrtf(var + 1e-5f);
    split_write(d0 * rs * g[tid] + be[tid], hi, lo, base + tid);
    split_write(d1 * rs * g[tid + 128] + be[tid + 128], hi, lo, base + tid + 128);
    split_write(d2 * rs * g[tid + 256] + be[tid + 256], hi, lo, base + tid + 256);
}

// ---------------- layernorm + length predictor on split buffer ---------------
__global__ __launch_bounds__(128) void ln_pred_split_k(
        const _Float16* __restrict__ hi, const _Float16* __restrict__ lo,
        const float* __restrict__ g, const float* __restrict__ be,
        const float* __restrict__ wl, const float* __restrict__ bl,
        const int* __restrict__ token_lengths, int* __restrict__ lns) {
    const int row = blockIdx.x;
    const int b = row >> 10, l = row & 1023;
    const size_t base = (size_t)(b * PADL + 1 + l) * DD;
    const int tid = threadIdx.x;
    float v0 = split_read(hi, lo, base + tid);
    float v1 = split_read(hi, lo, base + tid + 128);
    float v2 = split_read(hi, lo, base + tid + 256);

    __shared__ float sh[2];
    float s = v0 + v1 + v2;
    #pragma unroll
    for (int o = 32; o > 0; o >>= 1) s += __shfl_down(s, o, 64);
    if ((tid & 63) == 0) sh[tid >> 6] = s;
    __syncthreads();
    float mu = (sh[0] + sh[1]) * (1.f / DD);
    __syncthreads();
    float d0 = v0 - mu, d1 = v1 - mu, d2 = v2 - mu;
    float q = d0 * d0 + d1 * d1 + d2 * d2;
    #pragma unroll
    for (int o = 32; o > 0; o >>= 1) q += __shfl_down(q, o, 64);
    if ((tid & 63) == 0) sh[tid >> 6] = q;
    __syncthreads();
    float var = (sh[0] + sh[1]) * (1.f / DD);
    float rs = rsqrtf(var + 1e-5f);
    __syncthreads();
    float p = (d0 * rs * g[tid]       + be[tid])       * wl[tid]
            + (d1 * rs * g[tid + 128] + be[tid + 128]) * wl[tid + 128]
            + (d2 * rs * g[tid + 256] + be[tid + 256]) * wl[tid + 256];
    #pragma unroll
    for (int o = 32; o > 0; o >>= 1) p += __shfl_down(p, o, 64);
    if ((tid & 63) == 0) sh[tid >> 6] = p;
    __syncthreads();
    if (tid == 0) {
        float pred = sh[0] + sh[1] + bl[0];
        float e = expf(pred);           // ALPHA == 1.0
        float r = rintf(e);             // round-half-even, matches jnp.round
        r = fminf(fmaxf(r, 0.f), (float)MAX_DUR);
        int v = (int)r;
        if (l >= token_lengths[b]) v = 0;
        lns[row] = v;
    }
}

// ---------------- per-batch inclusive cumsum (L=1024) ------------------------
__global__ __launch_bounds__(1024) void cumsum_k(
        const int* __restrict__ lns, int* __restrict__ csum,
        float* __restrict__ totals_out) {
    __shared__ int s[1024];
    const int b = blockIdx.x, tid = threadIdx.x;
    s[tid] = lns[(b << 10) + tid];
    __syncthreads();
    #pragma unroll
    for (int o = 1; o < 1024; o <<= 1) {
        int t = (tid >= o) ? s[tid - o] : 0;
        __syncthreads();
        s[tid] += t;
        __syncthreads();
    }
    csum[(b << 10) + tid] = s[tid];
    if (tid == 1023) totals_out[b] = (float)s[1023];
}

// ---------------- gather: out[b,t,:] = valid ? y[b, idx(t), :] : 0 -----------
__global__ __launch_bounds__(256) void gather_k(
        const float* __restrict__ y, const int* __restrict__ csum,
        float* __restrict__ out) {
    int gid = blockIdx.x * 256 + threadIdx.x;   // B*T_OUT*96 float4 chunks
    int c4 = gid % 96;
    int rest = gid / 96;
    int t = rest % T_OUT;
    int b = rest / T_OUT;
    const int* c = csum + (b << 10);
    int total = c[1023];
    float4 r = make_float4(0.f, 0.f, 0.f, 0.f);
    if (t < total) {
        int lo = 0, hi = 1024;
        while (lo < hi) {               // searchsorted side='right'
            int mid = (lo + hi) >> 1;
            if (c[mid] <= t) lo = mid + 1; else hi = mid;
        }
        int idx = min(lo, LL - 1);
        r = *(const float4*)(y + ((size_t)((b << 10) + idx)) * DD + (c4 << 2));
    }
    *(float4*)(out + ((size_t)b * T_OUT + t) * DD + (c4 << 2)) = r;
}

// ---------------- host side --------------------------------------------------
extern "C" void kernel_launch(void* const* d_in, const int* in_sizes, int n_in,
                              void* d_out, int out_size, void* d_ws, size_t ws_size,
                              hipStream_t stream) {
    const float* y   = (const float*)d_in[0];
    const int*   tok = (const int*)d_in[1];
    const float* w1a = (const float*)d_in[2];
    const float* b1a = (const float*)d_in[3];
    const float* w1b = (const float*)d_in[4];
    const float* b1b = (const float*)d_in[5];
    const float* g1  = (const float*)d_in[6];
    const float* be1 = (const float*)d_in[7];
    const float* w2a = (const float*)d_in[8];
    const float* b2a = (const float*)d_in[9];
    const float* w2b = (const float*)d_in[10];
    const float* b2b = (const float*)d_in[11];
    const float* g2  = (const float*)d_in[12];
    const float* be2 = (const float*)d_in[13];
    const float* wl  = (const float*)d_in[14];
    const float* bl  = (const float*)d_in[15];

    float* out = (float*)d_out;

    // workspace layout (halfs)
    const size_t WN   = (size_t)FF * DD * KK;          // 1,769,472 per weight comp
    const size_t SN   = (size_t)BB * PADL * DD;        // 6,303,744
    const size_t H1N  = (size_t)BB * PADL * FF;        // 25,214,976
    _Float16* p = (_Float16*)d_ws;
    _Float16* Wh1a = p;              _Float16* Wl1a = Wh1a + WN;
    _Float16* Wh1b = Wl1a + WN;      _Float16* Wl1b = Wh1b + WN;
    _Float16* Wh2a = Wl1b + WN;      _Float16* Wl2a = Wh2a + WN;
    _Float16* Wh2b = Wl2a + WN;      _Float16* Wl2b = Wh2b + WN;
    _Float16* Shi  = Wl2b + WN;      _Float16* Slo  = Shi + SN;
    _Float16* H1hi = Slo + SN;       _Float16* H1lo = H1hi + H1N;
    int* lns  = (int*)(H1lo + H1N);
    int* csum = lns + BB * LL;

    const int M = BB * LL;                              // 16384

    // 1) weight frag-pack+split, y split, pad-zero for H1
    {
        int n = FF * DD * KK;
        wfrag_k<<<(n + 255) / 256, 256, 0, stream>>>(w1a, Wh1a, Wl1a, FF, DD);
        wfrag_k<<<(n + 255) / 256, 256, 0, stream>>>(w1b, Wh1b, Wl1b, DD, FF);
        wfrag_k<<<(n + 255) / 256, 256, 0, stream>>>(w2a, Wh2a, Wl2a, FF, DD);
        wfrag_k<<<(n + 255) / 256, 256, 0, stream>>>(w2b, Wh2b, Wl2b, DD, FF);
        int ny = BB * PADL * DD;
        ysplit_k<<<(ny + 255) / 256, 256, 0, stream>>>(y, Shi, Slo);
        int np = BB * 2 * FF;
        padzero_k<<<(np + 255) / 256, 256, 0, stream>>>(H1hi, H1lo, FF);
    }
    // 2) four conv-GEMMs (1-D grids, XCD-remapped in-kernel)
    //    D->F: MI=4 (BM=128) -> 1536 blocks = 3.0 rounds of 512 slots
    //    F->D: MI=2 (BM=64)  ->  768 blocks = 1.5 rounds, balanced (was 384 -> 33% tail)
    gemm_split<4><<<(FF / 128) * (M / 128), 256, 0, stream>>>(Shi, Slo, Wh1a, Wl1a, b1a, H1hi, H1lo, DD, FF, 3 * DD, FF / 128);
    gemm_split<2><<<(DD / 128) * (M / 64), 256, 0, stream>>>(H1hi, H1lo, Wh1b, Wl1b, b1b, Shi, Slo, FF, DD, 3 * FF, DD / 128);
    ln_split_k<<<M, 128, 0, stream>>>(Shi, Slo, g1, be1);
    gemm_split<4><<<(FF / 128) * (M / 128), 256, 0, stream>>>(Shi, Slo, Wh2a, Wl2a, b2a, H1hi, H1lo, DD, FF, 3 * DD, FF / 128);
    gemm_split<2><<<(DD / 128) * (M / 64), 256, 0, stream>>>(H1hi, H1lo, Wh2b, Wl2b, b2b, Shi, Slo, FF, DD, 3 * FF, DD / 128);
    // 3) predictor + cumsum + gather
    ln_pred_split_k<<<M, 128, 0, stream>>>(Shi, Slo, g2, be2, wl, bl, tok, lns);
    cumsum_k<<<BB, 1024, 0, stream>>>(lns, csum, out + (size_t)BB * T_OUT * DD);
    {
        long long n = (long long)BB * T_OUT * 96;
        gather_k<<<(int)((n + 255) / 256), 256, 0, stream>>>(y, csum, out);
    }
}

// Round 3
// 950.693 us; speedup vs baseline: 1.1274x; 1.0916x over previous
//
#include <hip/hip_runtime.h>
#include <hip/hip_bf16.h>

// Problem constants
#define BB 16
#define LL 1024
#define DD 384
#define FF 1536
#define KK 3
#define T_OUT 10240
#define MAX_DUR 10

#define PADL 1026                 // per-batch padded rows: [0]=zero, [1..1024]=data, [1025]=zero
#define LO_SCALE 2048.0f          // 2^11: keeps lo parts out of fp16-denormal range
#define LO_INV   4.8828125e-4f    // 2^-11

typedef _Float16 f16x8 __attribute__((ext_vector_type(8)));
typedef float    f32x4 __attribute__((ext_vector_type(4)));

__device__ __forceinline__ void gll16(const void* g, void* l) {
    __builtin_amdgcn_global_load_lds(
        (const __attribute__((address_space(1))) void*)g,
        (__attribute__((address_space(3))) void*)l, 16, 0, 0);
}

__device__ __forceinline__ void split_write(float v, _Float16* hi, _Float16* lo, size_t off) {
    _Float16 h = (_Float16)v;
    hi[off] = h;
    lo[off] = (_Float16)((v - (float)h) * LO_SCALE);
}

__device__ __forceinline__ float split_read(const _Float16* hi, const _Float16* lo, size_t off) {
    return (float)hi[off] + (float)lo[off] * LO_INV;
}

// ---- weight pack: (O,I,3) -> MFMA-fragment-major hi/lo --------------------
// frag layout: [o_tile][ktl][lane][e8], 8 halfs per lane (16 B), so a wave's
// b-frag load is base + lane*16 (one coalesced global_load_dwordx4).
// ktl ordering matches the GEMM k-loop: kseg = ktl%3 (fastest), d0 = (ktl/3)*32.
// lane: n_local = lane&15, k-quad = lane>>4; elem e: koff = kq*8 + e.
__global__ void wfrag_k(const float* __restrict__ w, _Float16* __restrict__ hi,
                        _Float16* __restrict__ lo, int O, int I) {
    int id = blockIdx.x * 256 + threadIdx.x;
    int total = O * 3 * I;
    if (id >= total) return;
    int e = id & 7;
    int lane = (id >> 3) & 63;
    int rest = id >> 9;              // o_tile * nKT + ktl
    int nKT = (3 * I) >> 5;
    int ktl = rest % nKT;
    int ot = rest / nKT;
    int o = ot * 16 + (lane & 15);
    int koff = ((lane >> 4) << 3) + e;
    int kseg = ktl % 3;
    int i = (ktl / 3) * 32 + koff;
    float v = w[(o * I + i) * 3 + kseg];
    split_write(v, hi, lo, id);
}

// ---------------- y split into padded hi/lo layout ---------------------------
__global__ void ysplit_k(const float* __restrict__ y, _Float16* __restrict__ hi,
                         _Float16* __restrict__ lo) {
    int id = blockIdx.x * 256 + threadIdx.x;     // BB*PADL*DD
    if (id >= BB * PADL * DD) return;
    int d = id % DD;
    int r = id / DD;
    int b = r / PADL;
    int lr = r - b * PADL;
    float v = 0.f;
    if (lr >= 1 && lr <= LL) v = y[((size_t)(b << 10) + (lr - 1)) * DD + d];
    split_write(v, hi, lo, id);
}

// ---------------- zero the halo pad rows of a padded split buffer ------------
__global__ void padzero_k(_Float16* __restrict__ hi, _Float16* __restrict__ lo, int width) {
    int id = blockIdx.x * 256 + threadIdx.x;     // BB*2*width
    if (id >= BB * 2 * width) return;
    int b = id / (2 * width);
    int rem = id - b * 2 * width;
    int row = (rem / width) ? (PADL - 1) : 0;
    int c = rem % width;
    size_t off = (size_t)(b * PADL + row) * width + c;
    hi[off] = (_Float16)0.f;
    lo[off] = (_Float16)0.f;
}

// ---------------- split-fp16 MFMA conv-GEMM ----------------------------------
// Traffic-minimized version (round-1 showed the k-loop is L2/L3-BW bound, not
// latency bound):
//  * A staged ONCE per d0 super-tile ((BM+2) rows, conv taps share it via
//    row+kseg reads) -> 3x less A global traffic.
//  * B staged into LDS (unique 16 KB per k-tile, linear frag-major chunks)
//    instead of per-wave register reloads -> 2x less B global traffic.
//  * 3 phases per super-tile; B double-buffered, overwritten only after the
//    post-compute barrier (write-after-all-reads). Counted vmcnt, issue order
//    pinned by sched_barrier(0) so the counts are exact:
//      phase s=0: keep 4 (B(kt+1));  s=1,2: keep NA+4 (A(j+1)+next B).
// OCC = min waves/EU: MI=2 uses 3 (49.7 KB LDS -> 3 blocks/CU; grid 768 =
// 256 CU x 3, one balanced round). MI=4 (66 KB LDS) stays at 2.
template<int MI, int OCC>
__global__ __launch_bounds__(256, OCC) void gemm_split(
        const _Float16* __restrict__ Ahi, const _Float16* __restrict__ Alo,
        const _Float16* __restrict__ WfH, const _Float16* __restrict__ WfL,
        const float* __restrict__ bias,
        _Float16* __restrict__ Ohi, _Float16* __restrict__ Olo,
        int Cin, int Cout, int Ktot, int nN) {
    constexpr int BM   = MI * 32;            // block M-rows (128 or 64)
    constexpr int AC   = (BM + 2) * 4;       // A 16B-chunks per comp (520 / 264)
    constexpr int AC4  = AC / 4;             // per-wave A chunks (130 / 66)
    constexpr int AIT  = (AC4 + 63) / 64;    // stage iters (3 / 2)
    constexpr int NA   = 2 * AIT;            // A gll16 per wave per stage (6 / 4)
    constexpr int AHH  = AC * 8;             // halfs per comp
    constexpr int ABH  = 4 * AHH;            // A region halfs (2 bufs x 2 comps)
    constexpr int KEEP0  = 4;                // vmcnt keep at phase s=0
    constexpr int KEEP12 = NA + 4;           // vmcnt keep at phases s=1,2
    __shared__ __align__(16) _Float16 lds_h[ABH + 2 * 8192];  // A dbuf | B dbuf
    const int tid = threadIdx.x;
    const int lane = tid & 63;
    const int w = tid >> 6;
    const int lm = lane & 15, lq = lane >> 4;
    // XCD-aware remap: group-of-4 m-tiles, n fastest inside the group
    const int xcd = blockIdx.x & 7;
    const int t2 = blockIdx.x >> 3;
    const int g  = t2 / (4 * nN);
    const int r  = t2 - g * (4 * nN);
    const int n_t = r >> 2;
    const int mi  = r & 3;
    const int m_t = ((g * 4 + mi) << 3) + xcd;
    const int m0 = m_t * BM;
    const int n0 = n_t << 7;
    const int b = m0 >> 10;
    const int l0 = m0 & 1023;
    const int rowBase = b * PADL + l0;           // padded source row of tap -1
    const int wm = (w >> 1) * (MI * 16), wn = (w & 1) * 64;

    f32x4 accM[MI][4], accC[MI][4];
    const f32x4 zz = {0.f, 0.f, 0.f, 0.f};
    #pragma unroll
    for (int i = 0; i < MI; ++i)
        #pragma unroll
        for (int jj = 0; jj < 4; ++jj) { accM[i][jj] = zz; accC[i][jj] = zz; }

    const int nKT = Ktot >> 5;
    const int nJ  = nKT / 3;                 // super-tiles (one per d0 group)

    // stage A super-tile jt ((BM+2) rows x 32 halfs x 2 comps) into buffer bidx
    auto stageA = [&](int jt, int bidx) {
        int d0 = jt << 5;
        _Float16* abase = lds_h + bidx * (2 * AHH);
        #pragma unroll
        for (int it = 0; it < AIT; ++it) {
            int cl = it * 64 + lane;                 // chunk within wave's range
            int s  = w * AC4 + cl;                   // global chunk id
            int p = s >> 3, sl = s & 7;
            int t = sl ^ (p & 7);
            int m = p * 2 + (t >> 2);
            int k8 = t & 3;
            size_t aoff = (size_t)(rowBase + m) * Cin + d0 + k8 * 8;
            _Float16* hb = abase + (size_t)(w * AC4 + it * 64) * 8;  // wave-uniform
            if (cl < AC4) {                          // >=2 lanes active: uniform vmcnt
                gll16(Ahi + aoff, hb);
                gll16(Alo + aoff, hb + AHH);
            }
        }
    };

    // stage B k-tile kt (8 ntg segs x 2 comps, 16 KB unique) into buffer bidx
    auto stageB = [&](int kt, int bidx) {
        int ktc = kt < nKT ? kt : nKT - 1;
        _Float16* bb = lds_h + ABH + bidx * 8192 + (w * 2) * 512;
        #pragma unroll
        for (int q = 0; q < 2; ++q) {
            int ntg = (n0 >> 4) + w * 2 + q;
            size_t boff = (((size_t)ntg * nKT + ktc) * 64 + lane) * 8;
            gll16(WfH + boff, bb + q * 512);
            gll16(WfL + boff, bb + 4096 + q * 512);
        }
    };

    // MFMA phase: A frags from ab (+kseg row shift), B frags from bb
    auto compute = [&](const _Float16* ab, const _Float16* bb, int kseg) {
        f16x8 bH[4], bL[4];
        #pragma unroll
        for (int jj = 0; jj < 4; ++jj) {
            int nl = (w & 1) * 4 + jj;
            bH[jj] = *(const f16x8*)(bb + nl * 512 + lane * 8);
            bL[jj] = *(const f16x8*)(bb + 4096 + nl * 512 + lane * 8);
        }
        __builtin_amdgcn_s_setprio(1);
        #pragma unroll
        for (int i = 0; i < MI; ++i) {
            int row = wm + i * 16 + lm + kseg;
            int p = row >> 1;
            int sl = (((row & 1) << 2) | lq) ^ (p & 7);
            int off = p * 64 + sl * 8;
            f16x8 aH = *(const f16x8*)(ab + off);
            f16x8 aL = *(const f16x8*)(ab + AHH + off);
            #pragma unroll
            for (int jj = 0; jj < 4; ++jj) {
                accM[i][jj] = __builtin_amdgcn_mfma_f32_16x16x32_f16(aH, bH[jj], accM[i][jj], 0, 0, 0);
                accC[i][jj] = __builtin_amdgcn_mfma_f32_16x16x32_f16(aH, bL[jj], accC[i][jj], 0, 0, 0);
                accC[i][jj] = __builtin_amdgcn_mfma_f32_16x16x32_f16(aL, bH[jj], accC[i][jj], 0, 0, 0);
            }
        }
        __builtin_amdgcn_s_setprio(0);
    };

    // prologue: B(0)->b0, A(0)->a0, B(1)->b1 (issue order pinned for vmcnt math)
    stageB(0, 0);
    __builtin_amdgcn_sched_barrier(0);
    stageA(0, 0);
    __builtin_amdgcn_sched_barrier(0);
    stageB(1, 1);
    __builtin_amdgcn_sched_barrier(0);

    for (int j = 0; j < nJ; ++j) {
        const _Float16* ab = lds_h + (j & 1) * (2 * AHH);
        const int kt = 3 * j;
        // ---- phase s=0: compute kt, then stage B(kt+2) + A(j+1) ----------
        asm volatile("s_waitcnt vmcnt(%0)" :: "i"(KEEP0) : "memory");
        __builtin_amdgcn_s_barrier();
        __builtin_amdgcn_sched_barrier(0);
        compute(ab, lds_h + ABH + (kt & 1) * 8192, 0);
        __builtin_amdgcn_sched_barrier(0);
        __builtin_amdgcn_s_barrier();
        stageB(kt + 2, kt & 1);                    // overwrite just-read buffer
        __builtin_amdgcn_sched_barrier(0);
        stageA(j + 1 < nJ ? j + 1 : j, (j + 1) & 1);
        __builtin_amdgcn_sched_barrier(0);
        // ---- phase s=1 ----------------------------------------------------
        asm volatile("s_waitcnt vmcnt(%0)" :: "i"(KEEP12) : "memory");
        __builtin_amdgcn_s_barrier();
        __builtin_amdgcn_sched_barrier(0);
        compute(ab, lds_h + ABH + ((kt + 1) & 1) * 8192, 1);
        __builtin_amdgcn_sched_barrier(0);
        __builtin_amdgcn_s_barrier();
        stageB(kt + 3, (kt + 1) & 1);
        __builtin_amdgcn_sched_barrier(0);
        // ---- phase s=2 ----------------------------------------------------
        asm volatile("s_waitcnt vmcnt(%0)" :: "i"(KEEP12) : "memory");
        __builtin_amdgcn_s_barrier();
        __builtin_amdgcn_sched_barrier(0);
        compute(ab, lds_h + ABH + (kt & 1) * 8192, 2);
        __builtin_amdgcn_sched_barrier(0);
        __builtin_amdgcn_s_barrier();
        stageB(kt + 4, kt & 1);
        __builtin_amdgcn_sched_barrier(0);
    }
    // epilogue: bias + relu + re-split to padded hi/lo output
    #pragma unroll
    for (int i = 0; i < MI; ++i)
        #pragma unroll
        for (int jj = 0; jj < 4; ++jj) {
            int n_g = n0 + wn + jj * 16 + lm;
            float bv = bias[n_g];
            #pragma unroll
            for (int rr = 0; rr < 4; ++rr) {
                int l = l0 + wm + i * 16 + lq * 4 + rr;
                float v = accM[i][jj][rr] + accC[i][jj][rr] * LO_INV + bv;
                v = fmaxf(v, 0.f);
                size_t off = (size_t)(b * PADL + 1 + l) * Cout + n_g;
                split_write(v, Ohi, Olo, off);
            }
        }
}

// ---------------- layernorm in place on split buffer (width 384) -------------
__global__ __launch_bounds__(128) void ln_split_k(
        _Float16* __restrict__ hi, _Float16* __restrict__ lo,
        const float* __restrict__ g, const float* __restrict__ be) {
    const int row = blockIdx.x;
    const int b = row >> 10, l = row & 1023;
    const size_t base = (size_t)(b * PADL + 1 + l) * DD;
    const int tid = threadIdx.x;
    float v0 = split_read(hi, lo, base + tid);
    float v1 = split_read(hi, lo, base + tid + 128);
    float v2 = split_read(hi, lo, base + tid + 256);

    __shared__ float sh[2];
    float s = v0 + v1 + v2;
    #pragma unroll
    for (int o = 32; o > 0; o >>= 1) s += __shfl_down(s, o, 64);
    if ((tid & 63) == 0) sh[tid >> 6] = s;
    __syncthreads();
    float mu = (sh[0] + sh[1]) * (1.f / DD);
    __syncthreads();
    float d0 = v0 - mu, d1 = v1 - mu, d2 = v2 - mu;
    float q = d0 * d0 + d1 * d1 + d2 * d2;
    #pragma unroll
    for (int o = 32; o > 0; o >>= 1) q += __shfl_down(q, o, 64);
    if ((tid & 63) == 0) sh[tid >> 6] = q;
    __syncthreads();
    float var = (sh[0] + sh[1]) * (1.f / DD);
    float rs = rsqrtf(var + 1e-5f);
    split_write(d0 * rs * g[tid] + be[tid], hi, lo, base + tid);
    split_write(d1 * rs * g[tid + 128] + be[tid + 128], hi, lo, base + tid + 128);
    split_write(d2 * rs * g[tid + 256] + be[tid + 256], hi, lo, base + tid + 256);
}

// ---------------- layernorm + length predictor on split buffer ---------------
__global__ __launch_bounds__(128) void ln_pred_split_k(
        const _Float16* __restrict__ hi, const _Float16* __restrict__ lo,
        const float* __restrict__ g, const float* __restrict__ be,
        const float* __restrict__ wl, const float* __restrict__ bl,
        const int* __restrict__ token_lengths, int* __restrict__ lns) {
    const int row = blockIdx.x;
    const int b = row >> 10, l = row & 1023;
    const size_t base = (size_t)(b * PADL + 1 + l) * DD;
    const int tid = threadIdx.x;
    float v0 = split_read(hi, lo, base + tid);
    float v1 = split_read(hi, lo, base + tid + 128);
    float v2 = split_read(hi, lo, base + tid + 256);

    __shared__ float sh[2];
    float s = v0 + v1 + v2;
    #pragma unroll
    for (int o = 32; o > 0; o >>= 1) s += __shfl_down(s, o, 64);
    if ((tid & 63) == 0) sh[tid >> 6] = s;
    __syncthreads();
    float mu = (sh[0] + sh[1]) * (1.f / DD);
    __syncthreads();
    float d0 = v0 - mu, d1 = v1 - mu, d2 = v2 - mu;
    float q = d0 * d0 + d1 * d1 + d2 * d2;
    #pragma unroll
    for (int o = 32; o > 0; o >>= 1) q += __shfl_down(q, o, 64);
    if ((tid & 63) == 0) sh[tid >> 6] = q;
    __syncthreads();
    float var = (sh[0] + sh[1]) * (1.f / DD);
    float rs = rsqrtf(var + 1e-5f);
    __syncthreads();
    float p = (d0 * rs * g[tid]       + be[tid])       * wl[tid]
            + (d1 * rs * g[tid + 128] + be[tid + 128]) * wl[tid + 128]
            + (d2 * rs * g[tid + 256] + be[tid + 256]) * wl[tid + 256];
    #pragma unroll
    for (int o = 32; o > 0; o >>= 1) p += __shfl_down(p, o, 64);
    if ((tid & 63) == 0) sh[tid >> 6] = p;
    __syncthreads();
    if (tid == 0) {
        float pred = sh[0] + sh[1] + bl[0];
        float e = expf(pred);           // ALPHA == 1.0
        float r = rintf(e);             // round-half-even, matches jnp.round
        r = fminf(fmaxf(r, 0.f), (float)MAX_DUR);
        int v = (int)r;
        if (l >= token_lengths[b]) v = 0;
        lns[row] = v;
    }
}

// ---------------- per-batch inclusive cumsum (L=1024) ------------------------
__global__ __launch_bounds__(1024) void cumsum_k(
        const int* __restrict__ lns, int* __restrict__ csum,
        float* __restrict__ totals_out) {
    __shared__ int s[1024];
    const int b = blockIdx.x, tid = threadIdx.x;
    s[tid] = lns[(b << 10) + tid];
    __syncthreads();
    #pragma unroll
    for (int o = 1; o < 1024; o <<= 1) {
        int t = (tid >= o) ? s[tid - o] : 0;
        __syncthreads();
        s[tid] += t;
        __syncthreads();
    }
    csum[(b << 10) + tid] = s[tid];
    if (tid == 1023) totals_out[b] = (float)s[1023];
}

// ---------------- gather: out[b,t,:] = valid ? y[b, idx(t), :] : 0 -----------
__global__ __launch_bounds__(256) void gather_k(
        const float* __restrict__ y, const int* __restrict__ csum,
        float* __restrict__ out) {
    int gid = blockIdx.x * 256 + threadIdx.x;   // B*T_OUT*96 float4 chunks
    int c4 = gid % 96;
    int rest = gid / 96;
    int t = rest % T_OUT;
    int b = rest / T_OUT;
    const int* c = csum + (b << 10);
    int total = c[1023];
    float4 r = make_float4(0.f, 0.f, 0.f, 0.f);
    if (t < total) {
        int lo = 0, hi = 1024;
        while (lo < hi) {               // searchsorted side='right'
            int mid = (lo + hi) >> 1;
            if (c[mid] <= t) lo = mid + 1; else hi = mid;
        }
        int idx = min(lo, LL - 1);
        r = *(const float4*)(y + ((size_t)((b << 10) + idx)) * DD + (c4 << 2));
    }
    *(float4*)(out + ((size_t)b * T_OUT + t) * DD + (c4 << 2)) = r;
}

// ---------------- host side --------------------------------------------------
extern "C" void kernel_launch(void* const* d_in, const int* in_sizes, int n_in,
                              void* d_out, int out_size, void* d_ws, size_t ws_size,
                              hipStream_t stream) {
    const float* y   = (const float*)d_in[0];
    const int*   tok = (const int*)d_in[1];
    const float* w1a = (const float*)d_in[2];
    const float* b1a = (const float*)d_in[3];
    const float* w1b = (const float*)d_in[4];
    const float* b1b = (const float*)d_in[5];
    const float* g1  = (const float*)d_in[6];
    const float* be1 = (const float*)d_in[7];
    const float* w2a = (const float*)d_in[8];
    const float* b2a = (const float*)d_in[9];
    const float* w2b = (const float*)d_in[10];
    const float* b2b = (const float*)d_in[11];
    const float* g2  = (const float*)d_in[12];
    const float* be2 = (const float*)d_in[13];
    const float* wl  = (const float*)d_in[14];
    const float* bl  = (const float*)d_in[15];

    float* out = (float*)d_out;

    // workspace layout (halfs)
    const size_t WN   = (size_t)FF * DD * KK;          // 1,769,472 per weight comp
    const size_t SN   = (size_t)BB * PADL * DD;        // 6,303,744
    const size_t H1N  = (size_t)BB * PADL * FF;        // 25,214,976
    _Float16* p = (_Float16*)d_ws;
    _Float16* Wh1a = p;              _Float16* Wl1a = Wh1a + WN;
    _Float16* Wh1b = Wl1a + WN;      _Float16* Wl1b = Wh1b + WN;
    _Float16* Wh2a = Wl1b + WN;      _Float16* Wl2a = Wh2a + WN;
    _Float16* Wh2b = Wl2a + WN;      _Float16* Wl2b = Wh2b + WN;
    _Float16* Shi  = Wl2b + WN;      _Float16* Slo  = Shi + SN;
    _Float16* H1hi = Slo + SN;       _Float16* H1lo = H1hi + H1N;
    int* lns  = (int*)(H1lo + H1N);
    int* csum = lns + BB * LL;

    const int M = BB * LL;                              // 16384

    // 1) weight frag-pack+split, y split, pad-zero for H1
    {
        int n = FF * DD * KK;
        wfrag_k<<<(n + 255) / 256, 256, 0, stream>>>(w1a, Wh1a, Wl1a, FF, DD);
        wfrag_k<<<(n + 255) / 256, 256, 0, stream>>>(w1b, Wh1b, Wl1b, DD, FF);
        wfrag_k<<<(n + 255) / 256, 256, 0, stream>>>(w2a, Wh2a, Wl2a, FF, DD);
        wfrag_k<<<(n + 255) / 256, 256, 0, stream>>>(w2b, Wh2b, Wl2b, DD, FF);
        int ny = BB * PADL * DD;
        ysplit_k<<<(ny + 255) / 256, 256, 0, stream>>>(y, Shi, Slo);
        int np = BB * 2 * FF;
        padzero_k<<<(np + 255) / 256, 256, 0, stream>>>(H1hi, H1lo, FF);
    }
    // 2) four conv-GEMMs (1-D grids, XCD-remapped in-kernel)
    //    D->F: MI=4 (BM=128), 1536 blocks = 3.0 rounds of 512 slots (2/CU)
    //    F->D: MI=2 (BM=64),   768 blocks = 1.0 round  of 768 slots (3/CU)
    gemm_split<4, 2><<<(FF / 128) * (M / 128), 256, 0, stream>>>(Shi, Slo, Wh1a, Wl1a, b1a, H1hi, H1lo, DD, FF, 3 * DD, FF / 128);
    gemm_split<2, 3><<<(DD / 128) * (M / 64), 256, 0, stream>>>(H1hi, H1lo, Wh1b, Wl1b, b1b, Shi, Slo, FF, DD, 3 * FF, DD / 128);
    ln_split_k<<<M, 128, 0, stream>>>(Shi, Slo, g1, be1);
    gemm_split<4, 2><<<(FF / 128) * (M / 128), 256, 0, stream>>>(Shi, Slo, Wh2a, Wl2a, b2a, H1hi, H1lo, DD, FF, 3 * DD, FF / 128);
    gemm_split<2, 3><<<(DD / 128) * (M / 64), 256, 0, stream>>>(H1hi, H1lo, Wh2b, Wl2b, b2b, Shi, Slo, FF, DD, 3 * FF, DD / 128);
    // 3) predictor + cumsum + gather
    ln_pred_split_k<<<M, 128, 0, stream>>>(Shi, Slo, g2, be2, wl, bl, tok, lns);
    cumsum_k<<<BB, 1024, 0, stream>>>(lns, csum, out + (size_t)BB * T_OUT * DD);
    {
        long long n = (long long)BB * T_OUT * 96;
        gather_k<<<(int)((n + 255) / 256), 256, 0, stream>>>(y, csum, out);
    }
}